// Round 5
// baseline (535.145 us; speedup 1.0000x reference)
//
#include <hip/hip_runtime.h>

// Problem constants (fixed by reference setup_inputs)
constexpr int B  = 4;
constexpr int C  = 128;    // == Cv
constexpr int hw = 16384;  // h*w = 128*128
constexpr int W_ = 256;
constexpr int HW = 65536;  // H*W
constexpr int K  = 16;
constexpr int P_TILE = 16;                       // positions per block
constexpr int BLOCKS_PER_BATCH = hw / P_TILE;    // 1024

// (C, HW) fp32 slice -> (HW, C) fp32, fully vectorized (float4 both sides),
// XOR-swizzled LDS tile: conflict-free writes (scalar, uniform 8 lanes/bank-4-group)
// and conflict-free b128 reads.
__global__ __launch_bounds__(256) void transpose_f32_v4(
    const float* __restrict__ src, float* __restrict__ dst)
{
    __shared__ float tile[64][64];   // [n_local][swizzled c-chunks], 16 KiB
    const int n0 = blockIdx.x * 64;
    const int c0 = blockIdx.y * 64;
    const int t  = threadIdx.x;

    // ---- load: float4 along N; c = 16*(t>>6) + 4*((t>>4)&3) + i ----
    const int n4 = t & 15;                 // float4 chunk along N
    const int crw = 16 * (t >> 6) + 4 * ((t >> 4) & 3);
    #pragma unroll
    for (int i = 0; i < 4; ++i) {
        const int c  = crw + i;
        const int ch = c >> 2, cl = c & 3;
        const float4 v = *reinterpret_cast<const float4*>(
            src + (size_t)(c0 + c) * HW + n0 + (n4 << 2));
        float vv[4] = {v.x, v.y, v.z, v.w};
        #pragma unroll
        for (int j = 0; j < 4; ++j) {
            const int n = (n4 << 2) + j;
            tile[n][((ch ^ (n & 15)) << 2) + cl] = vv[j];   // swizzled scatter, conflict-free
        }
    }
    __syncthreads();

    // ---- store: float4 along C; n = (t>>4) + 16*i ----
    const int c4r = t & 15;                // float4 chunk along C
    const int nb  = t >> 4;                // 0..15
    #pragma unroll
    for (int i = 0; i < 4; ++i) {
        const int n = nb + (i << 4);
        const int p = c4r ^ (n & 15);      // physical chunk
        const float4 v = *reinterpret_cast<const float4*>(&tile[n][p << 2]); // b128, conflict-free
        *reinterpret_cast<float4*>(dst + (size_t)(n0 + n) * C + c0 + (c4r << 2)) = v;
    }
}

// Gather-attention for ONE batch from transposed fp32 K/V slices (LLC-warm).
__global__ __launch_bounds__(256) void attn_gather(
    const float* __restrict__ Q, const int* __restrict__ Pos,
    const float* __restrict__ St, const float* __restrict__ Rt,
    float* __restrict__ outBuf, float* __restrict__ outM, int b)
{
    __shared__ float q_s[P_TILE][132];   // Q tile, fp32, padded (conflict-free float4)
    __shared__ float attn_s[P_TILE][17];
    __shared__ int   idx_s[P_TILE][K];
    __shared__ float out_s[P_TILE][132];

    const int tid = threadIdx.x;
    const int p0  = blockIdx.x * P_TILE;

    // ---- phase 0: stage Q tile (coalesced) + compute gather indices ----
    for (int i = tid; i < P_TILE * C; i += 256) {
        int c = i >> 4, pl0 = i & 15;
        q_s[pl0][c] = Q[((size_t)(b * C + c)) * hw + p0 + pl0];
    }
    const int pl = tid >> 4;   // position in tile
    const int kk = tid & 15;   // k index
    const int p  = p0 + pl;
    const int rr = Pos[(((size_t)(b * 2 + 0) * hw) + p) * K + kk];
    const int cc = Pos[(((size_t)(b * 2 + 1) * hw) + p) * K + kk];
    const int idx = rr * W_ + cc;
    idx_s[pl][kk] = idx;
    __syncthreads();

    // ---- phase 1: score = q . K_row (32 independent float4 loads), softmax over k ----
    float score = 0.f;
    {
        const float4* srow = reinterpret_cast<const float4*>(St + (size_t)idx * C);
        #pragma unroll
        for (int j = 0; j < 32; ++j) {
            float4 sv = srow[j];
            float4 qa = *reinterpret_cast<const float4*>(&q_s[pl][j * 4]);
            score += qa.x * sv.x + qa.y * sv.y + qa.z * sv.z + qa.w * sv.w;
        }
    }
    float mx = score;
    #pragma unroll
    for (int off = 1; off < 16; off <<= 1) mx = fmaxf(mx, __shfl_xor(mx, off));
    float e = __expf(score - mx);
    float ssum = e;
    #pragma unroll
    for (int off = 1; off < 16; off <<= 1) ssum += __shfl_xor(ssum, off);
    const float attn = e / ssum;
    outM[((size_t)b * hw + p) * K + kk] = attn;   // coalesced (contiguous per block)
    attn_s[pl][kk] = attn;
    __syncthreads();

    // ---- phase 2: out[c] = sum_k attn * V_row[c]; ping-pong groups of 4 rows ----
    {
        const int pl2 = tid >> 4;
        const int cg  = tid & 15;      // 8-channel chunk; 16 lanes span one 512B row
        float acc[8];
        #pragma unroll
        for (int i = 0; i < 8; ++i) acc[i] = 0.f;
        float4 cur[8], nxt[8];
        #pragma unroll
        for (int j = 0; j < 4; ++j) {
            const float4* rrow = reinterpret_cast<const float4*>(Rt + (size_t)idx_s[pl2][j] * C);
            cur[2 * j]     = rrow[cg * 2];
            cur[2 * j + 1] = rrow[cg * 2 + 1];
        }
        #pragma unroll
        for (int g = 0; g < 4; ++g) {
            if (g < 3) {
                #pragma unroll
                for (int j = 0; j < 4; ++j) {
                    const float4* rrow = reinterpret_cast<const float4*>(
                        Rt + (size_t)idx_s[pl2][4 * (g + 1) + j] * C);
                    nxt[2 * j]     = rrow[cg * 2];
                    nxt[2 * j + 1] = rrow[cg * 2 + 1];
                }
            }
            #pragma unroll
            for (int j = 0; j < 4; ++j) {
                const float a = attn_s[pl2][4 * g + j];
                acc[0] += a * cur[2 * j].x;     acc[1] += a * cur[2 * j].y;
                acc[2] += a * cur[2 * j].z;     acc[3] += a * cur[2 * j].w;
                acc[4] += a * cur[2 * j + 1].x; acc[5] += a * cur[2 * j + 1].y;
                acc[6] += a * cur[2 * j + 1].z; acc[7] += a * cur[2 * j + 1].w;
            }
            #pragma unroll
            for (int i = 0; i < 8; ++i) cur[i] = nxt[i];
        }
        #pragma unroll
        for (int i = 0; i < 8; ++i) out_s[pl2][cg * 8 + i] = acc[i];
    }
    __syncthreads();
    for (int i = tid; i < P_TILE * C; i += 256) {
        int c = i >> 4, pl3 = i & 15;
        outBuf[((size_t)(b * C + c)) * hw + p0 + pl3] = out_s[pl3][c];   // coalesced
    }
}

// Fallback: direct gather from original (B,C,H,W) layout. Slow but needs no workspace.
__global__ __launch_bounds__(256) void attn_direct(
    const float* __restrict__ Q, const float* __restrict__ S, const float* __restrict__ R,
    const int* __restrict__ Pos, float* __restrict__ outBuf, float* __restrict__ outM)
{
    __shared__ float q_s[P_TILE][132];
    __shared__ float attn_s[P_TILE][17];
    __shared__ int   idx_s[P_TILE][K];
    __shared__ float out_s[P_TILE][132];

    const int tid = threadIdx.x;
    const int b   = blockIdx.x / BLOCKS_PER_BATCH;
    const int p0  = (blockIdx.x % BLOCKS_PER_BATCH) * P_TILE;

    for (int i = tid; i < P_TILE * C; i += 256) {
        int c = i >> 4, pl0 = i & 15;
        q_s[pl0][c] = Q[((size_t)(b * C + c)) * hw + p0 + pl0];
    }
    const int pl = tid >> 4;
    const int kk = tid & 15;
    const int p  = p0 + pl;
    const int rr = Pos[(((size_t)(b * 2 + 0) * hw) + p) * K + kk];
    const int cc = Pos[(((size_t)(b * 2 + 1) * hw) + p) * K + kk];
    const int idx = rr * W_ + cc;
    idx_s[pl][kk] = idx;
    __syncthreads();

    float score = 0.f;
    {
        const float* srow = S + (size_t)b * C * HW + idx;
        for (int c = 0; c < C; ++c) score += q_s[pl][c] * srow[(size_t)c * HW];
    }
    float mx = score;
    #pragma unroll
    for (int off = 1; off < 16; off <<= 1) mx = fmaxf(mx, __shfl_xor(mx, off));
    float e = __expf(score - mx);
    float ssum = e;
    #pragma unroll
    for (int off = 1; off < 16; off <<= 1) ssum += __shfl_xor(ssum, off);
    const float attn = e / ssum;
    outM[((size_t)b * hw + p) * K + kk] = attn;
    attn_s[pl][kk] = attn;
    __syncthreads();

    {
        const int pl2 = tid >> 4;
        const int cg  = tid & 15;
        float acc[8];
        #pragma unroll
        for (int i = 0; i < 8; ++i) acc[i] = 0.f;
        for (int k2 = 0; k2 < K; ++k2) {
            const float a = attn_s[pl2][k2];
            const float* rw = R + (size_t)b * C * HW + idx_s[pl2][k2];
            #pragma unroll
            for (int i = 0; i < 8; ++i) acc[i] += a * rw[(size_t)(cg * 8 + i) * HW];
        }
        #pragma unroll
        for (int i = 0; i < 8; ++i) out_s[pl2][cg * 8 + i] = acc[i];
    }
    __syncthreads();
    for (int i = tid; i < P_TILE * C; i += 256) {
        int c = i >> 4, pl3 = i & 15;
        outBuf[((size_t)(b * C + c)) * hw + p0 + pl3] = out_s[pl3][c];
    }
}

extern "C" void kernel_launch(void* const* d_in, const int* in_sizes, int n_in,
                              void* d_out, int out_size, void* d_ws, size_t ws_size,
                              hipStream_t stream)
{
    (void)in_sizes; (void)n_in; (void)out_size;
    const float* Q  = (const float*)d_in[0];
    const float* S  = (const float*)d_in[1];
    const float* R  = (const float*)d_in[2];
    const int*  Pos = (const int*)d_in[3];
    float* outBuf = (float*)d_out;
    float* outM   = outBuf + (size_t)B * C * hw;   // buffer is B*Cv*h*w elements

    const size_t perBatch  = (size_t)HW * C;                       // 8,388,608 elems (32 MiB)
    const size_t fullBytes = 2 * (size_t)B * perBatch * sizeof(float);  // 256 MiB
    const size_t pairBytes = 2 * perBatch * sizeof(float);         // 64 MiB

    const dim3 tgrid(HW / 64, C / 64);   // 1024 x 2 = 2048 blocks per tensor-batch

    if (ws_size >= fullBytes) {
        // Per-batch pipeline over dedicated slices: gather b reads the 64 MiB its
        // transposes just wrote -> LLC-resident gathered rows.
        float* St = (float*)d_ws;
        float* Rt = St + (size_t)B * perBatch;
        for (int b = 0; b < B; ++b) {
            transpose_f32_v4<<<tgrid, 256, 0, stream>>>(S + (size_t)b * perBatch, St + (size_t)b * perBatch);
            transpose_f32_v4<<<tgrid, 256, 0, stream>>>(R + (size_t)b * perBatch, Rt + (size_t)b * perBatch);
            attn_gather<<<dim3(BLOCKS_PER_BATCH), 256, 0, stream>>>(
                Q, Pos, St + (size_t)b * perBatch, Rt + (size_t)b * perBatch, outBuf, outM, b);
        }
    } else if (ws_size >= pairBytes) {
        // Same pipeline, workspace slice reused per batch (stream serializes).
        float* St = (float*)d_ws;
        float* Rt = St + perBatch;
        for (int b = 0; b < B; ++b) {
            transpose_f32_v4<<<tgrid, 256, 0, stream>>>(S + (size_t)b * perBatch, St);
            transpose_f32_v4<<<tgrid, 256, 0, stream>>>(R + (size_t)b * perBatch, Rt);
            attn_gather<<<dim3(BLOCKS_PER_BATCH), 256, 0, stream>>>(
                Q, Pos, St, Rt, outBuf, outM, b);
        }
    } else {
        // no usable workspace: direct (uncoalesced) gather
        attn_direct<<<dim3(B * BLOCKS_PER_BATCH), 256, 0, stream>>>(
            Q, S, R, Pos, outBuf, outM);
    }
}